// Round 12
// baseline (239.337 us; speedup 1.0000x reference)
//
#include <hip/hip_runtime.h>
#include <hip/hip_bf16.h>

// TelephoneAttentionBlock: x[4,4096,1024] fp32 -> RMSNorm -> QKV (bf16 MFMA GEMM)
// -> windowed block attention (16 heads, dh=64, window 128) -> Wo GEMM + residual -> fp32 out.
// Round 12: R11's 32x32x16 GEMM with the swizzle-read bug FIXED. Stored LDS slot s of
// row r holds global slot s^(r&7); k-step j's slot is j*2+hi, so read byte must be
// ((j*2+hi) ^ (lane&7))*16 — full 3-bit XOR (R11 only XORed bit 0; lanes with
// (lane&7)>=2 read the wrong slot). Per-j base pointers precomputed (named, rule 20).

typedef __attribute__((ext_vector_type(8))) short s8v;    // 8 bf16 (4 VGPRs)
typedef __attribute__((ext_vector_type(4))) float f4v;    // 16x16 accumulator
typedef __attribute__((ext_vector_type(16))) float f16v;  // 32x32 accumulator

#define MFMA_BF16(A, B, C) __builtin_amdgcn_mfma_f32_16x16x32_bf16((A), (B), (C), 0, 0, 0)
#define MFMA32_BF16(A, B, C) __builtin_amdgcn_mfma_f32_32x32x16_bf16((A), (B), (C), 0, 0, 0)

static __device__ __forceinline__ void gload_lds16(const void* g, void* l) {
    // async global->LDS, 16B per lane; LDS dest = wave-uniform base + lane*16
    __builtin_amdgcn_global_load_lds((const __attribute__((address_space(1))) void*)g,
                                     (__attribute__((address_space(3))) void*)l, 16, 0, 0);
}

static __device__ __forceinline__ unsigned short f2bf(float f) {
    return __builtin_bit_cast(unsigned short, __float2bfloat16(f));
}

// ---------------- prep: rmsnorm (blocks [0,16384)) + weight transposes (rest) ----------------
__global__ __launch_bounds__(256) void prep_kernel(const float* __restrict__ x,
                                                   const float* __restrict__ g,
                                                   unsigned short* __restrict__ xn,
                                                   const float* __restrict__ Wqkv,
                                                   unsigned short* __restrict__ WqkvT,
                                                   const float* __restrict__ Wo,
                                                   unsigned short* __restrict__ WoT) {
    const int D = 1024, M = 16384;
    if (blockIdx.x < (unsigned)M) {
        // ---- RMSNorm row ----
        int row = blockIdx.x;
        int t = threadIdx.x;
        float4 v = ((const float4*)(x + (size_t)row * D))[t];
        float ss = v.x * v.x + v.y * v.y + v.z * v.z + v.w * v.w;
#pragma unroll
        for (int off = 32; off >= 1; off >>= 1) ss += __shfl_xor(ss, off, 64);
        __shared__ float partials[4];
        if ((t & 63) == 0) partials[t >> 6] = ss;
        __syncthreads();
        float tot = partials[0] + partials[1] + partials[2] + partials[3];
        float scale = rsqrtf(tot * (1.0f / D) + 1e-6f);
        float4 gv = ((const float4*)g)[t];
        ushort4 o;
        o.x = f2bf(v.x * scale * gv.x);
        o.y = f2bf(v.y * scale * gv.y);
        o.z = f2bf(v.z * scale * gv.z);
        o.w = f2bf(v.w * scale * gv.w);
        ((ushort4*)xn)[(size_t)row * (D / 4) + t] = o;
    } else {
        // ---- weight transpose: in[K][N] fp32 -> out[N][K] bf16 ----
        int nb1 = (D >> 5) * (3072 >> 5);
        int bidx = blockIdx.x - M;
        const float* in;
        unsigned short* out;
        int N;
        if (bidx < nb1) {
            in = Wqkv; out = WqkvT; N = 3072;
        } else {
            in = Wo; out = WoT; N = 1024; bidx -= nb1;
        }
        __shared__ float tile[32][33];
        int nbk = D >> 5;
        int bk = bidx % nbk;
        int bn = bidx / nbk;
        int tx = threadIdx.x & 31, ty = threadIdx.x >> 5;
#pragma unroll
        for (int i = 0; i < 4; i++) {
            int r = ty + i * 8;
            tile[r][tx] = in[(size_t)(bk * 32 + r) * N + bn * 32 + tx];
        }
        __syncthreads();
#pragma unroll
        for (int i = 0; i < 4; i++) {
            int r = ty + i * 8;
            out[(size_t)(bn * 32 + r) * D + bk * 32 + tx] = f2bf(tile[tx][r]);
        }
    }
}

// ---------------- GEMM 256x256, BK=64, 8-phase counted-vmcnt, 32x32x16 MFMA ----------------
// C[M][N] = A[M][K] * Bt[N][K]^T. MODE 0: C -> bf16. MODE 1: C -> fp32 = resid + acc.
// 512 threads = 8 waves (2M x 4N); per-wave 128x64 output = 4 m-frags(32) x 2 n-frags(32),
// acc = f32x16[4][2] (128 regs). Staging/swizzle-store/barrier schedule identical to R5.
// A/B frag: row = lane&31, k = (lane>>5)*8 + e (contiguous 8, mirrors verified 16x16x32).
// C/D frag: col = lane&31, row = (reg&3) + 8*(reg>>2) + 4*(lane>>5)  [m74/m101 verified].
// Swizzle READ (fixed): k-step j's global slot = j*2+hi; stored at slot (j*2+hi)^(row&7);
// byte = ((j*2+hi)^(lane&7))*16. row&7 == lane&7 for both A and B rows (offsets ≡ 0 mod 8).
template <int MODE>
__global__ __launch_bounds__(512, 2) void gemm256_kernel(const unsigned short* __restrict__ A,
                                                         const unsigned short* __restrict__ Bt,
                                                         unsigned short* __restrict__ Cb,
                                                         float* __restrict__ Cf,
                                                         const float* __restrict__ resid,
                                                         int M, int N, int K) {
    __shared__ __align__(16) char lds_s[131072];

    const int nbn = N >> 8;
    const int nwg = (M >> 8) * nbn;
    int bid = blockIdx.x;
    int cpx = nwg >> 3;                        // grids are multiples of 8
    int wg = (bid & 7) * cpx + (bid >> 3);     // XCD-aware swizzle (bijective)
    int bm = wg / nbn, bn = wg % nbn;

    int tid = threadIdx.x, lane = tid & 63, w = tid >> 6;
    int wm = w >> 2, wn = w & 3;               // wave tile: rows wm*128, cols wn*64
    int l31 = lane & 31, hi = lane >> 5, l7 = lane & 7;

    const unsigned short* Ab = A + (size_t)bm * 256 * K;
    const unsigned short* Bb = Bt + (size_t)bn * 256 * K;

    // staging lane geometry (unchanged from R5): 8 rows x 8 swizzled 16B slots per 64 lanes
    int srow = lane >> 3;
    int scol = ((lane & 7) ^ srow) * 8;

    // read-side swizzled byte offsets per k-step j (FIXED: full 3-bit slot XOR)
    int sw0 = ((0 | hi) ^ l7) << 4;
    int sw1 = ((2 | hi) ^ l7) << 4;
    int sw2 = ((4 | hi) ^ l7) << 4;
    int sw3 = ((6 | hi) ^ l7) << 4;
    const char* ldsA_0 = lds_s + wm * 16384 + l31 * 128 + sw0;
    const char* ldsA_1 = lds_s + wm * 16384 + l31 * 128 + sw1;
    const char* ldsA_2 = lds_s + wm * 16384 + l31 * 128 + sw2;
    const char* ldsA_3 = lds_s + wm * 16384 + l31 * 128 + sw3;
    const char* ldsB_0 = lds_s + 32768 + (wn * 64 + l31) * 128 + sw0;
    const char* ldsB_1 = lds_s + 32768 + (wn * 64 + l31) * 128 + sw1;
    const char* ldsB_2 = lds_s + 32768 + (wn * 64 + l31) * 128 + sw2;
    const char* ldsB_3 = lds_s + 32768 + (wn * 64 + l31) * 128 + sw3;

    const int NT = K >> 6;                     // 16 K-tiles for K=1024

    f16v acc[4][2] = {};
    s8v bfr[2][4];

#define STAGE(t_, isB_, h_) do {                                                          \
        int te_ = (t_) < NT ? (t_) : (t_)-NT;                                             \
        const unsigned short* g_ = ((isB_) ? Bb : Ab)                                     \
            + (size_t)((h_)*128 + srow) * K + te_ * 64 + scol;                            \
        char* l_ = lds_s + (((t_)&1) * 65536 + (isB_)*32768 + (h_)*16384);                \
        gload_lds16(g_ + (size_t)(w * 8) * K, l_ + w * 1024);                             \
        gload_lds16(g_ + (size_t)(64 + w * 8) * K, l_ + 8192 + w * 1024);                 \
    } while (0)

// one phase = m-frag p4_: 4 x ds_read_b128 (A), phase 0 also 8 x (B); 8 MFMA 32x32x16.
#define PHASE(buf_, p4_, st_, sb_, sh_, dv_) do {                                         \
        s8v a0 = *(const s8v*)(ldsA_0 + (buf_)*65536 + (p4_)*4096);                       \
        s8v a1 = *(const s8v*)(ldsA_1 + (buf_)*65536 + (p4_)*4096);                       \
        s8v a2 = *(const s8v*)(ldsA_2 + (buf_)*65536 + (p4_)*4096);                       \
        s8v a3 = *(const s8v*)(ldsA_3 + (buf_)*65536 + (p4_)*4096);                       \
        if ((p4_) == 0) {                                                                 \
            _Pragma("unroll") for (int nf = 0; nf < 2; nf++) {                            \
                bfr[nf][0] = *(const s8v*)(ldsB_0 + (buf_)*65536 + nf * 4096);            \
                bfr[nf][1] = *(const s8v*)(ldsB_1 + (buf_)*65536 + nf * 4096);            \
                bfr[nf][2] = *(const s8v*)(ldsB_2 + (buf_)*65536 + nf * 4096);            \
                bfr[nf][3] = *(const s8v*)(ldsB_3 + (buf_)*65536 + nf * 4096);            \
            }                                                                             \
        }                                                                                 \
        STAGE(st_, sb_, sh_);                                                             \
        if (dv_) asm volatile("s_waitcnt vmcnt(4)" ::: "memory");                         \
        asm volatile("s_barrier" ::: "memory");                                           \
        asm volatile("s_waitcnt lgkmcnt(0)" ::: "memory");                                \
        __builtin_amdgcn_s_setprio(1);                                                    \
        acc[p4_][0] = MFMA32_BF16(a0, bfr[0][0], acc[p4_][0]);                            \
        acc[p4_][1] = MFMA32_BF16(a0, bfr[1][0], acc[p4_][1]);                            \
        acc[p4_][0] = MFMA32_BF16(a1, bfr[0][1], acc[p4_][0]);                            \
        acc[p4_][1] = MFMA32_BF16(a1, bfr[1][1], acc[p4_][1]);                            \
        acc[p4_][0] = MFMA32_BF16(a2, bfr[0][2], acc[p4_][0]);                            \
        acc[p4_][1] = MFMA32_BF16(a2, bfr[1][2], acc[p4_][1]);                            \
        acc[p4_][0] = MFMA32_BF16(a3, bfr[0][3], acc[p4_][0]);                            \
        acc[p4_][1] = MFMA32_BF16(a3, bfr[1][3], acc[p4_][1]);                            \
        __builtin_amdgcn_s_setprio(0);                                                    \
        asm volatile("s_barrier" ::: "memory");                                           \
    } while (0)

    STAGE(0, 0, 0); STAGE(0, 0, 1); STAGE(0, 1, 0); STAGE(0, 1, 1);
    STAGE(1, 1, 0); STAGE(1, 1, 1);
    asm volatile("s_waitcnt vmcnt(4)" ::: "memory");
    asm volatile("s_barrier" ::: "memory");

    for (int i = 0; i < NT / 2; i++) {
        int t1 = 2 * i + 1;
        PHASE(0, 0, t1, 0, 0, 0);
        PHASE(0, 1, t1, 0, 1, 0);
        PHASE(0, 2, t1 + 1, 1, 0, 0);
        PHASE(0, 3, t1 + 1, 1, 1, 1);   // vmcnt(4): tile t1 fully arrived
        PHASE(1, 0, t1 + 1, 0, 0, 0);
        PHASE(1, 1, t1 + 1, 0, 1, 0);
        PHASE(1, 2, t1 + 2, 1, 0, 0);
        PHASE(1, 3, t1 + 2, 1, 1, 1);   // vmcnt(4): tile 2i+2 fully arrived
    }
#undef PHASE
#undef STAGE

    // epilogue: C write (32x32 C/D layout; lanes 0-31 -> contiguous cols per row)
    int crow0 = bm * 256 + wm * 128 + hi * 4;
    int ccol0 = bn * 256 + wn * 64 + l31;
#pragma unroll
    for (int m = 0; m < 4; m++) {
#pragma unroll
        for (int n = 0; n < 2; n++) {
#pragma unroll
            for (int reg = 0; reg < 16; reg++) {
                int row = crow0 + m * 32 + (reg & 3) + ((reg >> 2) << 3);
                int col = ccol0 + n * 32;
                float val = acc[m][n][reg];
                if (MODE == 0) {
                    Cb[(size_t)row * N + col] = f2bf(val);
                } else {
                    size_t idx = (size_t)row * N + col;
                    Cf[idx] = resid[idx] + val;
                }
            }
        }
    }
}

// ---------------- windowed block attention (band-limited, R5/R10 proven) ----------------
// grid: B*H*NB blocks; 256 threads = 4 waves x 32 query rows.
// Per m-frag (16 queries at frag index m0 = 2w+mf), only key frags m0..m0+8 are unmasked.
// LDS: [0,32768) K [256 keys][64 dh] XOR-swizzled (reused as Vt [64][264] swizzled after QK^T);
//      [33792, 44032) per-wave P staging [32][40].
__global__ __launch_bounds__(256, 3) void attn_kernel(const unsigned short* __restrict__ qkv,
                                                      unsigned short* __restrict__ obuf) {
    constexpr int S = 4096, D = 1024, H = 16, W = 128, NB = 32;
    constexpr int TD = 3 * D;
    constexpr int PS = 40;

    __shared__ __align__(16) char smem[44032];
    unsigned short* KV = (unsigned short*)smem;

    int bid = blockIdx.x;
    int blk = bid % NB;
    int h = (bid / NB) % H;
    int b = bid / (NB * H);

    int tid = threadIdx.x, lane = tid & 63, w = tid >> 6;
    int hl = lane >> 4, ll = lane & 15;
    unsigned short* Ps = (unsigned short*)(smem + 33792) + w * 32 * PS;

    int kbase = blk * W - W;            // global s of extended key 0
    size_t rowbase = (size_t)(b * S);

    // ---- stage K [256][64] via async global_load_lds, source pre-swizzled ----
    {
        int lr = lane >> 3;                       // row within 8-row chunk
        int scb = ((lane & 7) ^ lr) * 16;         // swizzled source byte col
#pragma unroll
        for (int r = 0; r < 8; r++) {
            int row = r * 32 + w * 8 + lr;        // ext key index
            int s = kbase + row;
            s = s < 0 ? 0 : s;                    // clamp (blk 0: masked later, finite data)
            const char* src = (const char*)(qkv + (rowbase + s) * TD + D + h * 64) + scb;
            char* dst = smem + (size_t)(r * 32 + w * 8) * 128 + lane * 16;
            gload_lds16(src, dst);
        }
    }

    // ---- Q fragments ----
    s8v qf[2][2];
    {
        const unsigned short* qb = qkv + (rowbase + blk * W + w * 32) * TD + h * 64;
#pragma unroll
        for (int mf = 0; mf < 2; mf++)
#pragma unroll
            for (int ks = 0; ks < 2; ks++)
                qf[mf][ks] = *(const s8v*)(qb + (size_t)(mf * 16 + ll) * TD + ks * 32 + hl * 8);
    }

    // ---- prefetch V into regs: lane owns 8x8 block V[k0..k0+7][d0..d0+7] ----
    s8v vreg[8];
    {
        int k0 = w * 64 + (lane >> 3) * 8;
        int d0 = (lane & 7) * 8;
#pragma unroll
        for (int it = 0; it < 8; it++) {
            int s = kbase + k0 + it;
            s = s < 0 ? 0 : s;
            vreg[it] = *(const s8v*)(qkv + (rowbase + s) * TD + 2 * D + h * 64 + d0);
        }
    }
    __syncthreads();   // K in LDS (V regs also arrived)

    // ---- QK^T: band of 9 key frags per m-frag; kf shared across mf via 10-frag sweep ----
    f4v sc[2][9] = {};
    int g0 = w * 2;
    __builtin_amdgcn_s_setprio(1);
#pragma unroll
    for (int gi = 0; gi < 10; gi++) {
#pragma unroll
        for (int ks = 0; ks < 2; ks++) {
            int row = (g0 + gi) * 16 + ll;
            s8v kf = *(const s8v*)(smem + (size_t)row * 128 +
                                   (((unsigned)(ks * 64 + hl * 16)) ^ ((ll & 7) << 4)));
            if (gi < 9) sc[0][gi] = MFMA_BF16(qf[0][ks], kf, sc[0][gi]);
            if (gi > 0) sc[1][gi - 1] = MFMA_BF16(qf[1][ks], kf, sc[1][gi - 1]);
        }
    }
    __builtin_amdgcn_s_setprio(0);

    // ---- mask + scale + softmax (rows across 16 lanes of quarter-wave) ----
    float linv[2][4];
#pragma unroll
    for (int mf = 0; mf < 2; mf++) {
#pragma unroll
        for (int r = 0; r < 4; r++) {
            int ip = hl * 4 + r;                  // query pos within m-frag
            float mx = -1e30f;
#pragma unroll
            for (int nf = 0; nf < 9; nf++) {
                bool ok = (nf > 0 || ll > ip) && (nf < 8 || ll <= ip) &&
                          (blk > 0 || (g0 + mf + nf) >= 8);
                float sval = ok ? sc[mf][nf][r] * 0.125f : -1e30f;
                sc[mf][nf][r] = sval;
                mx = fmaxf(mx, sval);
            }
#pragma unroll
            for (int off = 1; off < 16; off <<= 1) mx = fmaxf(mx, __shfl_xor(mx, off, 64));
            float sum = 0.f;
#pragma unroll
            for (int nf = 0; nf < 9; nf++) {
                float p = __expf(sc[mf][nf][r] - mx);
                sc[mf][nf][r] = p;
                sum += p;
            }
#pragma unroll
            for (int off = 1; off < 16; off <<= 1) sum += __shfl_xor(sum, off, 64);
            linv[mf][r] = 1.f / sum;
        }
    }

    __syncthreads();   // all waves done reading K

    // ---- write V transposed: in-register 8x8 transpose, 8 x ds_write_b128 ----
    // Vt[d][k'] with k' = k ^ (((d>>3)&7)<<3); read side applies the same XOR.
    {
        int k0 = w * 64 + (lane >> 3) * 8;
        int d0 = (lane & 7) * 8;
#pragma unroll
        for (int e = 0; e < 8; e++) {
            int d = d0 + e;
            s8v tmp;
#pragma unroll
            for (int i = 0; i < 8; i++) tmp[i] = vreg[i][e];
            *(s8v*)(KV + d * 264 + (k0 ^ (((d >> 3) & 7) << 3))) = tmp;
        }
    }
    __syncthreads();   // Vt visible

    // ---- PV: 5 chunks of 32 keys starting at wave base w*32 ----
    f4v o[2][4] = {};
#pragma unroll
    for (int c = 0; c < 5; c++) {
#pragma unroll
        for (int mf = 0; mf < 2; mf++) {
#pragma unroll
            for (int j16 = 0; j16 < 2; j16++) {
                int nf = c * 2 + j16 - mf;
                int nfc = nf < 0 ? 0 : (nf > 8 ? 8 : nf);
#pragma unroll
                for (int r = 0; r < 4; r++) {
                    float val = (nf >= 0 && nf < 9) ? sc[mf][nfc][r] : 0.f;
                    Ps[(mf * 16 + hl * 4 + r) * PS + j16 * 16 + ll] = f2bf(val);
                }
            }
        }
        asm volatile("s_waitcnt lgkmcnt(0)" ::: "memory");
        s8v pa[2];
        pa[0] = *(const s8v*)(Ps + ll * PS + hl * 8);
        pa[1] = *(const s8v*)(Ps + (16 + ll) * PS + hl * 8);
        int cb = (w + c) * 32;
        __builtin_amdgcn_s_setprio(1);
#pragma unroll
        for (int nd = 0; nd < 4; nd++) {
            int d = nd * 16 + ll;
            int kk = (cb + hl * 8) ^ (((d >> 3) & 7) << 3);
            s8v vb = *(const s8v*)(KV + d * 264 + kk);
            o[0][nd] = MFMA_BF16(pa[0], vb, o[0][nd]);
            o[1][nd] = MFMA_BF16(pa[1], vb, o[1][nd]);
        }
        __builtin_amdgcn_s_setprio(0);
    }

    // ---- write O (bf16) ----
    unsigned short* ob = obuf + (rowbase + blk * W + w * 32) * D + h * 64;
#pragma unroll
    for (int mf = 0; mf < 2; mf++)
#pragma unroll
        for (int r = 0; r < 4; r++) {
            int row = mf * 16 + hl * 4 + r;
#pragma unroll
            for (int nd = 0; nd < 4; nd++)
                ob[(size_t)row * D + nd * 16 + ll] = f2bf(o[mf][nd][r] * linv[mf][r]);
        }
}

// ---------------- launch ----------------
extern "C" void kernel_launch(void* const* d_in, const int* in_sizes, int n_in,
                              void* d_out, int out_size, void* d_ws, size_t ws_size,
                              hipStream_t stream) {
    const float* x = (const float*)d_in[0];
    const float* g = (const float*)d_in[1];
    const float* Wqkv = (const float*)d_in[2];
    const float* Wo = (const float*)d_in[3];
    float* out = (float*)d_out;

    const int S = 4096, D = 1024, B = 4;
    const int M = B * S;  // 16384
    const int N3 = 3 * D; // 3072

    // workspace layout (bytes):
    //   [0, 6291456)            WqkvT bf16 [3072][1024]
    //   [6291456, 8388608)      WoT   bf16 [1024][1024]
    //   [8388608, 41943040)     xn    bf16 [16384][1024]  (reused as attention output)
    //   [41943040, 142606336)   qkv   bf16 [16384][3072]
    char* ws = (char*)d_ws;
    unsigned short* WqkvT = (unsigned short*)ws;
    unsigned short* WoT = (unsigned short*)(ws + 6291456);
    unsigned short* xn = (unsigned short*)(ws + 8388608);
    unsigned short* qkv = (unsigned short*)(ws + 41943040);

    int prep_grid = M + (D / 32) * (N3 / 32) + (D / 32) * (D / 32);
    prep_kernel<<<dim3(prep_grid), dim3(256), 0, stream>>>(x, g, xn, Wqkv, WqkvT, Wo, WoT);
    gemm256_kernel<0><<<dim3((M / 256) * (N3 / 256)), dim3(512), 0, stream>>>(
        xn, WqkvT, qkv, nullptr, nullptr, M, N3, D);
    attn_kernel<<<dim3(B * 16 * (S / 128)), dim3(256), 0, stream>>>(qkv, xn);
    gemm256_kernel<1><<<dim3((M / 256) * (D / 256)), dim3(512), 0, stream>>>(
        xn, WoT, nullptr, out, x, M, D, D);
}

// Round 13
// 207.021 us; speedup vs baseline: 1.1561x; 1.1561x over previous
//
#include <hip/hip_runtime.h>
#include <hip/hip_bf16.h>

// TelephoneAttentionBlock: x[4,4096,1024] fp32 -> RMSNorm -> QKV (bf16 MFMA GEMM)
// -> windowed block attention (16 heads, dh=64, window 128) -> Wo GEMM + residual -> fp32 out.
// Round 13: FINAL lock-in = R10 composite (best known, 207.7 us, reproduced twice).
// GEMM = 8-phase 256^2 counted-vmcnt 16x16x32 (41% MfmaUtil, 0 bank conflicts);
// attn = 256-thread band-9 kernel; prep = fused rmsnorm + weight transposes.
// (R12's 32x32x16 variant was correct but 9.4e6 LDS bank conflicts made it slower.)

typedef __attribute__((ext_vector_type(8))) short s8v;   // 8 bf16 (4 VGPRs)
typedef __attribute__((ext_vector_type(4))) float f4v;   // MFMA accumulator

#define MFMA_BF16(A, B, C) __builtin_amdgcn_mfma_f32_16x16x32_bf16((A), (B), (C), 0, 0, 0)

static __device__ __forceinline__ void gload_lds16(const void* g, void* l) {
    // async global->LDS, 16B per lane; LDS dest = wave-uniform base + lane*16
    __builtin_amdgcn_global_load_lds((const __attribute__((address_space(1))) void*)g,
                                     (__attribute__((address_space(3))) void*)l, 16, 0, 0);
}

static __device__ __forceinline__ unsigned short f2bf(float f) {
    return __builtin_bit_cast(unsigned short, __float2bfloat16(f));
}

// ---------------- prep: rmsnorm (blocks [0,16384)) + weight transposes (rest) ----------------
__global__ __launch_bounds__(256) void prep_kernel(const float* __restrict__ x,
                                                   const float* __restrict__ g,
                                                   unsigned short* __restrict__ xn,
                                                   const float* __restrict__ Wqkv,
                                                   unsigned short* __restrict__ WqkvT,
                                                   const float* __restrict__ Wo,
                                                   unsigned short* __restrict__ WoT) {
    const int D = 1024, M = 16384;
    if (blockIdx.x < (unsigned)M) {
        // ---- RMSNorm row ----
        int row = blockIdx.x;
        int t = threadIdx.x;
        float4 v = ((const float4*)(x + (size_t)row * D))[t];
        float ss = v.x * v.x + v.y * v.y + v.z * v.z + v.w * v.w;
#pragma unroll
        for (int off = 32; off >= 1; off >>= 1) ss += __shfl_xor(ss, off, 64);
        __shared__ float partials[4];
        if ((t & 63) == 0) partials[t >> 6] = ss;
        __syncthreads();
        float tot = partials[0] + partials[1] + partials[2] + partials[3];
        float scale = rsqrtf(tot * (1.0f / D) + 1e-6f);
        float4 gv = ((const float4*)g)[t];
        ushort4 o;
        o.x = f2bf(v.x * scale * gv.x);
        o.y = f2bf(v.y * scale * gv.y);
        o.z = f2bf(v.z * scale * gv.z);
        o.w = f2bf(v.w * scale * gv.w);
        ((ushort4*)xn)[(size_t)row * (D / 4) + t] = o;
    } else {
        // ---- weight transpose: in[K][N] fp32 -> out[N][K] bf16 ----
        int nb1 = (D >> 5) * (3072 >> 5);
        int bidx = blockIdx.x - M;
        const float* in;
        unsigned short* out;
        int N;
        if (bidx < nb1) {
            in = Wqkv; out = WqkvT; N = 3072;
        } else {
            in = Wo; out = WoT; N = 1024; bidx -= nb1;
        }
        __shared__ float tile[32][33];
        int nbk = D >> 5;
        int bk = bidx % nbk;
        int bn = bidx / nbk;
        int tx = threadIdx.x & 31, ty = threadIdx.x >> 5;
#pragma unroll
        for (int i = 0; i < 4; i++) {
            int r = ty + i * 8;
            tile[r][tx] = in[(size_t)(bk * 32 + r) * N + bn * 32 + tx];
        }
        __syncthreads();
#pragma unroll
        for (int i = 0; i < 4; i++) {
            int r = ty + i * 8;
            out[(size_t)(bn * 32 + r) * D + bk * 32 + tx] = f2bf(tile[tx][r]);
        }
    }
}

// ---------------- GEMM 256x256, BK=64, 8-phase counted-vmcnt (R5/R10 proven) ----------------
template <int MODE>
__global__ __launch_bounds__(512, 2) void gemm256_kernel(const unsigned short* __restrict__ A,
                                                         const unsigned short* __restrict__ Bt,
                                                         unsigned short* __restrict__ Cb,
                                                         float* __restrict__ Cf,
                                                         const float* __restrict__ resid,
                                                         int M, int N, int K) {
    __shared__ __align__(16) char lds_s[131072];

    const int nbn = N >> 8;
    const int nwg = (M >> 8) * nbn;
    int bid = blockIdx.x;
    int cpx = nwg >> 3;
    int wg = (bid & 7) * cpx + (bid >> 3);
    int bm = wg / nbn, bn = wg % nbn;

    int tid = threadIdx.x, lane = tid & 63, w = tid >> 6;
    int wm = w >> 2, wn = w & 3;
    int hl = lane >> 4, ll = lane & 15;

    const unsigned short* Ab = A + (size_t)bm * 256 * K;
    const unsigned short* Bb = Bt + (size_t)bn * 256 * K;

    int srow = lane >> 3;
    int scol = ((lane & 7) ^ srow) * 8;

    int c0 = (hl * 16) ^ ((ll & 7) * 16);
    const char* ldsA0 = lds_s + wm * 16384 + ll * 128 + c0;
    const char* ldsA1 = lds_s + wm * 16384 + ll * 128 + (c0 ^ 64);
    const char* ldsB0 = lds_s + 32768 + (wn >> 1) * 16384 + ((wn & 1) * 64 + ll) * 128 + c0;
    const char* ldsB1 = lds_s + 32768 + (wn >> 1) * 16384 + ((wn & 1) * 64 + ll) * 128 + (c0 ^ 64);

    const int NT = K >> 6;

    f4v acc[8][4] = {};
    s8v bfr[4][2];

#define STAGE(t_, isB_, h_) do {                                                          \
        int te_ = (t_) < NT ? (t_) : (t_)-NT;                                             \
        const unsigned short* g_ = ((isB_) ? Bb : Ab)                                     \
            + (size_t)((h_)*128 + srow) * K + te_ * 64 + scol;                            \
        char* l_ = lds_s + (((t_)&1) * 65536 + (isB_)*32768 + (h_)*16384);                \
        gload_lds16(g_ + (size_t)(w * 8) * K, l_ + w * 1024);                             \
        gload_lds16(g_ + (size_t)(64 + w * 8) * K, l_ + 8192 + w * 1024);                 \
    } while (0)

#define PHASE(buf_, p4_, st_, sb_, sh_, dv_) do {                                         \
        s8v a0k0 = *(const s8v*)(ldsA0 + (buf_)*65536 + (2 * (p4_)) * 2048);              \
        s8v a0k1 = *(const s8v*)(ldsA1 + (buf_)*65536 + (2 * (p4_)) * 2048);              \
        s8v a1k0 = *(const s8v*)(ldsA0 + (buf_)*65536 + (2 * (p4_) + 1) * 2048);          \
        s8v a1k1 = *(const s8v*)(ldsA1 + (buf_)*65536 + (2 * (p4_) + 1) * 2048);          \
        if ((p4_) == 0) {                                                                 \
            _Pragma("unroll") for (int n = 0; n < 4; n++) {                               \
                bfr[n][0] = *(const s8v*)(ldsB0 + (buf_)*65536 + n * 2048);               \
                bfr[n][1] = *(const s8v*)(ldsB1 + (buf_)*65536 + n * 2048);               \
            }                                                                             \
        }                                                                                 \
        STAGE(st_, sb_, sh_);                                                             \
        if (dv_) asm volatile("s_waitcnt vmcnt(4)" ::: "memory");                         \
        asm volatile("s_barrier" ::: "memory");                                           \
        asm volatile("s_waitcnt lgkmcnt(0)" ::: "memory");                                \
        __builtin_amdgcn_s_setprio(1);                                                    \
        _Pragma("unroll") for (int n = 0; n < 4; n++) {                                   \
            acc[2 * (p4_)][n] = MFMA_BF16(a0k0, bfr[n][0], acc[2 * (p4_)][n]);            \
            acc[2 * (p4_)][n] = MFMA_BF16(a0k1, bfr[n][1], acc[2 * (p4_)][n]);            \
            acc[2 * (p4_) + 1][n] = MFMA_BF16(a1k0, bfr[n][0], acc[2 * (p4_) + 1][n]);    \
            acc[2 * (p4_) + 1][n] = MFMA_BF16(a1k1, bfr[n][1], acc[2 * (p4_) + 1][n]);    \
        }                                                                                 \
        __builtin_amdgcn_s_setprio(0);                                                    \
        asm volatile("s_barrier" ::: "memory");                                           \
    } while (0)

    STAGE(0, 0, 0); STAGE(0, 0, 1); STAGE(0, 1, 0); STAGE(0, 1, 1);
    STAGE(1, 1, 0); STAGE(1, 1, 1);
    asm volatile("s_waitcnt vmcnt(4)" ::: "memory");
    asm volatile("s_barrier" ::: "memory");

    for (int i = 0; i < NT / 2; i++) {
        int t1 = 2 * i + 1;
        PHASE(0, 0, t1, 0, 0, 0);
        PHASE(0, 1, t1, 0, 1, 0);
        PHASE(0, 2, t1 + 1, 1, 0, 0);
        PHASE(0, 3, t1 + 1, 1, 1, 1);
        PHASE(1, 0, t1 + 1, 0, 0, 0);
        PHASE(1, 1, t1 + 1, 0, 1, 0);
        PHASE(1, 2, t1 + 2, 1, 0, 0);
        PHASE(1, 3, t1 + 2, 1, 1, 1);
    }
#undef PHASE
#undef STAGE

    int crow0 = bm * 256 + wm * 128;
    int ccol0 = bn * 256 + wn * 64;
#pragma unroll
    for (int m = 0; m < 8; m++) {
#pragma unroll
        for (int r = 0; r < 4; r++) {
            int row = crow0 + m * 16 + hl * 4 + r;
#pragma unroll
            for (int n = 0; n < 4; n++) {
                int col = ccol0 + n * 16 + ll;
                float val = acc[m][n][r];
                if (MODE == 0) {
                    Cb[(size_t)row * N + col] = f2bf(val);
                } else {
                    size_t idx = (size_t)row * N + col;
                    Cf[idx] = resid[idx] + val;
                }
            }
        }
    }
}

// ---------------- windowed block attention (band-limited, R5/R10 proven) ----------------
// grid: B*H*NB blocks; 256 threads = 4 waves x 32 query rows.
// Per m-frag (16 queries at frag index m0 = 2w+mf), only key frags m0..m0+8 are unmasked.
// LDS: [0,32768) K [256 keys][64 dh] XOR-swizzled (reused as Vt [64][264] swizzled after QK^T);
//      [33792, 44032) per-wave P staging [32][40].
__global__ __launch_bounds__(256, 3) void attn_kernel(const unsigned short* __restrict__ qkv,
                                                      unsigned short* __restrict__ obuf) {
    constexpr int S = 4096, D = 1024, H = 16, W = 128, NB = 32;
    constexpr int TD = 3 * D;
    constexpr int PS = 40;

    __shared__ __align__(16) char smem[44032];
    unsigned short* KV = (unsigned short*)smem;

    int bid = blockIdx.x;
    int blk = bid % NB;
    int h = (bid / NB) % H;
    int b = bid / (NB * H);

    int tid = threadIdx.x, lane = tid & 63, w = tid >> 6;
    int hl = lane >> 4, ll = lane & 15;
    unsigned short* Ps = (unsigned short*)(smem + 33792) + w * 32 * PS;

    int kbase = blk * W - W;            // global s of extended key 0
    size_t rowbase = (size_t)(b * S);

    // ---- stage K [256][64] via async global_load_lds, source pre-swizzled ----
    {
        int lr = lane >> 3;                       // row within 8-row chunk
        int scb = ((lane & 7) ^ lr) * 16;         // swizzled source byte col
#pragma unroll
        for (int r = 0; r < 8; r++) {
            int row = r * 32 + w * 8 + lr;        // ext key index
            int s = kbase + row;
            s = s < 0 ? 0 : s;                    // clamp (blk 0: masked later, finite data)
            const char* src = (const char*)(qkv + (rowbase + s) * TD + D + h * 64) + scb;
            char* dst = smem + (size_t)(r * 32 + w * 8) * 128 + lane * 16;
            gload_lds16(src, dst);
        }
    }

    // ---- Q fragments ----
    s8v qf[2][2];
    {
        const unsigned short* qb = qkv + (rowbase + blk * W + w * 32) * TD + h * 64;
#pragma unroll
        for (int mf = 0; mf < 2; mf++)
#pragma unroll
            for (int ks = 0; ks < 2; ks++)
                qf[mf][ks] = *(const s8v*)(qb + (size_t)(mf * 16 + ll) * TD + ks * 32 + hl * 8);
    }

    // ---- prefetch V into regs: lane owns 8x8 block V[k0..k0+7][d0..d0+7] ----
    s8v vreg[8];
    {
        int k0 = w * 64 + (lane >> 3) * 8;
        int d0 = (lane & 7) * 8;
#pragma unroll
        for (int it = 0; it < 8; it++) {
            int s = kbase + k0 + it;
            s = s < 0 ? 0 : s;
            vreg[it] = *(const s8v*)(qkv + (rowbase + s) * TD + 2 * D + h * 64 + d0);
        }
    }
    __syncthreads();   // K in LDS (V regs also arrived)

    // ---- QK^T: band of 9 key frags per m-frag; kf shared across mf via 10-frag sweep ----
    f4v sc[2][9] = {};
    int g0 = w * 2;
    __builtin_amdgcn_s_setprio(1);
#pragma unroll
    for (int gi = 0; gi < 10; gi++) {
#pragma unroll
        for (int ks = 0; ks < 2; ks++) {
            int row = (g0 + gi) * 16 + ll;
            s8v kf = *(const s8v*)(smem + (size_t)row * 128 +
                                   (((unsigned)(ks * 64 + hl * 16)) ^ ((ll & 7) << 4)));
            if (gi < 9) sc[0][gi] = MFMA_BF16(qf[0][ks], kf, sc[0][gi]);
            if (gi > 0) sc[1][gi - 1] = MFMA_BF16(qf[1][ks], kf, sc[1][gi - 1]);
        }
    }
    __builtin_amdgcn_s_setprio(0);

    // ---- mask + scale + softmax (rows across 16 lanes of quarter-wave) ----
    float linv[2][4];
#pragma unroll
    for (int mf = 0; mf < 2; mf++) {
#pragma unroll
        for (int r = 0; r < 4; r++) {
            int ip = hl * 4 + r;                  // query pos within m-frag
            float mx = -1e30f;
#pragma unroll
            for (int nf = 0; nf < 9; nf++) {
                bool ok = (nf > 0 || ll > ip) && (nf < 8 || ll <= ip) &&
                          (blk > 0 || (g0 + mf + nf) >= 8);
                float sval = ok ? sc[mf][nf][r] * 0.125f : -1e30f;
                sc[mf][nf][r] = sval;
                mx = fmaxf(mx, sval);
            }
#pragma unroll
            for (int off = 1; off < 16; off <<= 1) mx = fmaxf(mx, __shfl_xor(mx, off, 64));
            float sum = 0.f;
#pragma unroll
            for (int nf = 0; nf < 9; nf++) {
                float p = __expf(sc[mf][nf][r] - mx);
                sc[mf][nf][r] = p;
                sum += p;
            }
#pragma unroll
            for (int off = 1; off < 16; off <<= 1) sum += __shfl_xor(sum, off, 64);
            linv[mf][r] = 1.f / sum;
        }
    }

    __syncthreads();   // all waves done reading K

    // ---- write V transposed: in-register 8x8 transpose, 8 x ds_write_b128 ----
    // Vt[d][k'] with k' = k ^ (((d>>3)&7)<<3); read side applies the same XOR.
    {
        int k0 = w * 64 + (lane >> 3) * 8;
        int d0 = (lane & 7) * 8;
#pragma unroll
        for (int e = 0; e < 8; e++) {
            int d = d0 + e;
            s8v tmp;
#pragma unroll
            for (int i = 0; i < 8; i++) tmp[i] = vreg[i][e];
            *(s8v*)(KV + d * 264 + (k0 ^ (((d >> 3) & 7) << 3))) = tmp;
        }
    }
    __syncthreads();   // Vt visible

    // ---- PV: 5 chunks of 32 keys starting at wave base w*32 ----
    f4v o[2][4] = {};
#pragma unroll
    for (int c = 0; c < 5; c++) {
#pragma unroll
        for (int mf = 0; mf < 2; mf++) {
#pragma unroll
            for (int j16 = 0; j16 < 2; j16++) {
                int nf = c * 2 + j16 - mf;
                int nfc = nf < 0 ? 0 : (nf > 8 ? 8 : nf);
#pragma unroll
                for (int r = 0; r < 4; r++) {
                    float val = (nf >= 0 && nf < 9) ? sc[mf][nfc][r] : 0.f;
                    Ps[(mf * 16 + hl * 4 + r) * PS + j16 * 16 + ll] = f2bf(val);
                }
            }
        }
        asm volatile("s_waitcnt lgkmcnt(0)" ::: "memory");
        s8v pa[2];
        pa[0] = *(const s8v*)(Ps + ll * PS + hl * 8);
        pa[1] = *(const s8v*)(Ps + (16 + ll) * PS + hl * 8);
        int cb = (w + c) * 32;
        __builtin_amdgcn_s_setprio(1);
#pragma unroll
        for (int nd = 0; nd < 4; nd++) {
            int d = nd * 16 + ll;
            int kk = (cb + hl * 8) ^ (((d >> 3) & 7) << 3);
            s8v vb = *(const s8v*)(KV + d * 264 + kk);
            o[0][nd] = MFMA_BF16(pa[0], vb, o[0][nd]);
            o[1][nd] = MFMA_BF16(pa[1], vb, o[1][nd]);
        }
        __builtin_amdgcn_s_setprio(0);
    }

    // ---- write O (bf16) ----
    unsigned short* ob = obuf + (rowbase + blk * W + w * 32) * D + h * 64;
#pragma unroll
    for (int mf = 0; mf < 2; mf++)
#pragma unroll
        for (int r = 0; r < 4; r++) {
            int row = mf * 16 + hl * 4 + r;
#pragma unroll
            for (int nd = 0; nd < 4; nd++)
                ob[(size_t)row * D + nd * 16 + ll] = f2bf(o[mf][nd][r] * linv[mf][r]);
        }
}

// ---------------- launch ----------------
extern "C" void kernel_launch(void* const* d_in, const int* in_sizes, int n_in,
                              void* d_out, int out_size, void* d_ws, size_t ws_size,
                              hipStream_t stream) {
    const float* x = (const float*)d_in[0];
    const float* g = (const float*)d_in[1];
    const float* Wqkv = (const float*)d_in[2];
    const float* Wo = (const float*)d_in[3];
    float* out = (float*)d_out;

    const int S = 4096, D = 1024, B = 4;
    const int M = B * S;  // 16384
    const int N3 = 3 * D; // 3072

    // workspace layout (bytes):
    //   [0, 6291456)            WqkvT bf16 [3072][1024]
    //   [6291456, 8388608)      WoT   bf16 [1024][1024]
    //   [8388608, 41943040)     xn    bf16 [16384][1024]  (reused as attention output)
    //   [41943040, 142606336)   qkv   bf16 [16384][3072]
    char* ws = (char*)d_ws;
    unsigned short* WqkvT = (unsigned short*)ws;
    unsigned short* WoT = (unsigned short*)(ws + 6291456);
    unsigned short* xn = (unsigned short*)(ws + 8388608);
    unsigned short* qkv = (unsigned short*)(ws + 41943040);

    int prep_grid = M + (D / 32) * (N3 / 32) + (D / 32) * (D / 32);
    prep_kernel<<<dim3(prep_grid), dim3(256), 0, stream>>>(x, g, xn, Wqkv, WqkvT, Wo, WoT);
    gemm256_kernel<0><<<dim3((M / 256) * (N3 / 256)), dim3(512), 0, stream>>>(
        xn, WqkvT, qkv, nullptr, nullptr, M, N3, D);
    attn_kernel<<<dim3(B * 16 * (S / 128)), dim3(256), 0, stream>>>(qkv, xn);
    gemm256_kernel<1><<<dim3((M / 256) * (D / 256)), dim3(512), 0, stream>>>(
        xn, WoT, nullptr, out, x, M, D, D);
}